// Round 1
// baseline (427.263 us; speedup 1.0000x reference)
//
#include <hip/hip_runtime.h>
#include <math.h>

// Problem constants (from reference): D=256, DIN=512, F=16
#define DD 256
#define REPS 8   // replicated accumulators to reduce atomic same-address contention

// Workspace layout (float offsets)
#define OFF_SUMREP 0        // 2 inputs * REPS * 256 = 4096
#define OFF_H1     4096     // 2 * 256 = 512
#define OFF_S1REP  4608     // 4096
#define OFF_H2     8704     // 512
#define OFF_OREP   9216     // 4096
#define OFF_O      13312    // 512  (o1 then o2)
#define OFF_WTREP  13824    // REPS * 16 = 128
#define WS_FLOATS  13952

__device__ __forceinline__ float sigmoidf_(float x) { return 1.0f / (1.0f + __expf(-x)); }

__device__ __forceinline__ float wave_sum(float v) {
#pragma unroll
    for (int off = 32; off; off >>= 1) v += __shfl_xor(v, off, 64);
    return v;
}

__global__ void k_zero(float* __restrict__ ws) {
    int i = blockIdx.x * 256 + threadIdx.x;
    if (i < WS_FLOATS) ws[i] = 0.0f;
}

// Pass A: column sums of x1 and x2. Grid = 1024 blocks x 256 thr; blocks<512 -> x1.
__global__ void k_mean(const float* __restrict__ x1, const float* __restrict__ x2,
                       int N1, int N2, float* __restrict__ ws) {
    int b = blockIdx.x, t = threadIdx.x;
    int inp = (b < 512) ? 0 : 1;
    int bl = inp ? (b - 512) : b;
    const float4* x = (const float4*)(inp ? x2 : x1);
    int N = inp ? N2 : N1;
    int col4 = t & 63;          // this thread always owns columns 4*col4 .. +3
    int rg = t >> 6;            // row-group within block (0..3)
    float4 acc = make_float4(0.f, 0.f, 0.f, 0.f);
    for (int r = bl * 4 + rg; r < N; r += 2048) {
        float4 v = x[(size_t)r * 64 + col4];
        acc.x += v.x; acc.y += v.y; acc.z += v.z; acc.w += v.w;
    }
    __shared__ float4 lds[256];
    lds[t] = acc;
    __syncthreads();
    if (t < 64) {
        float4 s = lds[t];
        float4 a = lds[t + 64], c = lds[t + 128], d = lds[t + 192];
        s.x += a.x + c.x + d.x; s.y += a.y + c.y + d.y;
        s.z += a.z + c.z + d.z; s.w += a.w + c.w + d.w;
        float* dst = ws + OFF_SUMREP + inp * (REPS * 256) + (bl & (REPS - 1)) * 256 + t * 4;
        atomicAdd(dst + 0, s.x); atomicAdd(dst + 1, s.y);
        atomicAdd(dst + 2, s.z); atomicAdd(dst + 3, s.w);
    }
}

// h = tanh((acc/N) @ W0). Grid = 2 blocks (one per input) x 256 thr.
__global__ void k_h(const float* __restrict__ W0, float* __restrict__ ws,
                    int srcOff, int dstOff, int N1, int N2) {
    int inp = blockIdx.x, t = threadIdx.x;
    __shared__ float temp[256];
    const float* src = ws + srcOff + inp * (REPS * 256);
    float s = 0.f;
#pragma unroll
    for (int r = 0; r < REPS; r++) s += src[r * 256 + t];
    temp[t] = s * (1.0f / (float)(inp ? N2 : N1));
    __syncthreads();
    // 4 independent accumulators to keep loads in flight / break FMA chain
    float h0 = 0.f, h1 = 0.f, h2 = 0.f, h3 = 0.f;
#pragma unroll 4
    for (int d = 0; d < 256; d += 4) {
        h0 += temp[d + 0] * W0[(d + 0) * 256 + t];
        h1 += temp[d + 1] * W0[(d + 1) * 256 + t];
        h2 += temp[d + 2] * W0[(d + 2) * 256 + t];
        h3 += temp[d + 3] * W0[(d + 3) * 256 + t];
    }
    ws[dstOff + inp * 256 + t] = tanhf((h0 + h1) + (h2 + h3));
}

// Pass B: s1 = sum_i sigmoid(x_i . h1) * x_i.  Wave-per-row.
__global__ void k_att1(const float* __restrict__ x1, const float* __restrict__ x2,
                       int N1, int N2, float* __restrict__ ws) {
    int b = blockIdx.x, t = threadIdx.x;
    int inp = (b < 512) ? 0 : 1;
    int bl = inp ? (b - 512) : b;
    const float4* x = (const float4*)(inp ? x2 : x1);
    int N = inp ? N2 : N1;
    int lane = t & 63, w = t >> 6;
    float4 h1 = ((const float4*)(ws + OFF_H1 + inp * 256))[lane];
    float4 acc = make_float4(0.f, 0.f, 0.f, 0.f);
    for (int r = bl * 4 + w; r < N; r += 2048) {
        float4 v = x[(size_t)r * 64 + lane];
        float d = v.x * h1.x + v.y * h1.y + v.z * h1.z + v.w * h1.w;
        d = wave_sum(d);
        float att = sigmoidf_(d);
        acc.x += att * v.x; acc.y += att * v.y; acc.z += att * v.z; acc.w += att * v.w;
    }
    __shared__ float4 lds[256];
    lds[t] = acc;
    __syncthreads();
    if (t < 64) {
        float4 s = lds[t];
        float4 a = lds[t + 64], c = lds[t + 128], d = lds[t + 192];
        s.x += a.x + c.x + d.x; s.y += a.y + c.y + d.y;
        s.z += a.z + c.z + d.z; s.w += a.w + c.w + d.w;
        float* dst = ws + OFF_S1REP + inp * (REPS * 256) + (bl & (REPS - 1)) * 256 + t * 4;
        atomicAdd(dst + 0, s.x); atomicAdd(dst + 1, s.y);
        atomicAdd(dst + 2, s.z); atomicAdd(dst + 3, s.w);
    }
}

// Pass C: o = sum_i att1_i*att2_i*x_i, att2_i = sigmoid(att1_i * (x_i . h2)).
__global__ void k_att2(const float* __restrict__ x1, const float* __restrict__ x2,
                       int N1, int N2, float* __restrict__ ws) {
    int b = blockIdx.x, t = threadIdx.x;
    int inp = (b < 512) ? 0 : 1;
    int bl = inp ? (b - 512) : b;
    const float4* x = (const float4*)(inp ? x2 : x1);
    int N = inp ? N2 : N1;
    int lane = t & 63, w = t >> 6;
    float4 h1 = ((const float4*)(ws + OFF_H1 + inp * 256))[lane];
    float4 h2 = ((const float4*)(ws + OFF_H2 + inp * 256))[lane];
    float4 acc = make_float4(0.f, 0.f, 0.f, 0.f);
    for (int r = bl * 4 + w; r < N; r += 2048) {
        float4 v = x[(size_t)r * 64 + lane];
        float d1 = v.x * h1.x + v.y * h1.y + v.z * h1.z + v.w * h1.w;
        float d2 = v.x * h2.x + v.y * h2.y + v.z * h2.z + v.w * h2.w;
#pragma unroll
        for (int off = 32; off; off >>= 1) {
            d1 += __shfl_xor(d1, off, 64);
            d2 += __shfl_xor(d2, off, 64);
        }
        float att1 = sigmoidf_(d1);
        float att2 = sigmoidf_(att1 * d2);
        float wgt = att1 * att2;
        acc.x += wgt * v.x; acc.y += wgt * v.y; acc.z += wgt * v.z; acc.w += wgt * v.w;
    }
    __shared__ float4 lds[256];
    lds[t] = acc;
    __syncthreads();
    if (t < 64) {
        float4 s = lds[t];
        float4 a = lds[t + 64], c = lds[t + 128], d = lds[t + 192];
        s.x += a.x + c.x + d.x; s.y += a.y + c.y + d.y;
        s.z += a.z + c.z + d.z; s.w += a.w + c.w + d.w;
        float* dst = ws + OFF_OREP + inp * (REPS * 256) + (bl & (REPS - 1)) * 256 + t * 4;
        atomicAdd(dst + 0, s.x); atomicAdd(dst + 1, s.y);
        atomicAdd(dst + 2, s.z); atomicAdd(dst + 3, s.w);
    }
}

// Combine o replicas -> o1[256], o2[256]
__global__ void k_comb(float* __restrict__ ws) {
    int t = threadIdx.x;           // 512 threads
    int inp = t >> 8, c = t & 255;
    float s = 0.f;
#pragma unroll
    for (int r = 0; r < REPS; r++) s += ws[OFF_OREP + inp * (REPS * 256) + r * 256 + c];
    ws[OFF_O + t] = s;
}

// w_term[f] = sum_{d,e} g1[d] W[f,d,e] g2[e], with g=[o,o] duplication folded.
// Rows (f,d): 16*512 = 8192 rows of 512 floats. Wave-per-row.
__global__ void k_ntn(const float* __restrict__ W, float* __restrict__ ws) {
    int b = blockIdx.x, t = threadIdx.x;
    int lane = t & 63, w = t >> 6;
    const float* o1 = ws + OFF_O;
    float4 o2f = ((const float4*)(ws + OFF_O + 256))[lane];
    for (int row = b * 4 + w; row < 8192; row += 2048) {
        int f = row >> 9, d = row & 511;
        const float4* Wr = (const float4*)(W + (size_t)row * 512);
        float4 a = Wr[lane];        // e = 4*lane .. +3
        float4 c = Wr[lane + 64];   // e = 256+4*lane .. +3   (g2 repeats o2)
        float p = (a.x + c.x) * o2f.x + (a.y + c.y) * o2f.y
                + (a.z + c.z) * o2f.z + (a.w + c.w) * o2f.w;
        p = wave_sum(p);
        if (lane == 0)
            atomicAdd(ws + OFF_WTREP + (b & (REPS - 1)) * 16 + f, o1[d & 255] * p);
    }
}

// v_term + w_term + b -> sigmoid -> 4-layer MLP -> out[0]
__global__ void k_final(const float* __restrict__ V, const float* __restrict__ bb,
                        const float* __restrict__ P0, const float* __restrict__ P1,
                        const float* __restrict__ P2, const float* __restrict__ P3,
                        float* __restrict__ ws, float* __restrict__ out) {
    int t = threadIdx.x;           // 256 threads
    const float* o = ws + OFF_O;
    int f = t >> 4, j = t & 15;
    float p = 0.f;
    for (int k = j; k < 1024; k += 16) {
        float cv = (k < 512) ? o[k & 255] : o[256 + (k & 255)];
        p += cv * V[f * 1024 + k];
    }
    __shared__ float red[256];
    __shared__ float sv[16];
    red[t] = p;
    __syncthreads();
    if (t < 16) {
        float v = 0.f;
#pragma unroll
        for (int q = 0; q < 16; q++) v += red[t * 16 + q];
        float wt = 0.f;
#pragma unroll
        for (int r = 0; r < REPS; r++) wt += ws[OFF_WTREP + r * 16 + t];
        sv[t] = sigmoidf_(v + wt + bb[t]);
    }
    __syncthreads();
    if (t == 0) {
        float y0[8], y1[4], y2[2];
#pragma unroll
        for (int i = 0; i < 8; i++) {
            float s = 0.f;
            for (int k = 0; k < 16; k++) s += P0[i * 16 + k] * sv[k];
            y0[i] = sigmoidf_(s);
        }
#pragma unroll
        for (int i = 0; i < 4; i++) {
            float s = 0.f;
            for (int k = 0; k < 8; k++) s += P1[i * 8 + k] * y0[k];
            y1[i] = sigmoidf_(s);
        }
#pragma unroll
        for (int i = 0; i < 2; i++) {
            float s = 0.f;
            for (int k = 0; k < 4; k++) s += P2[i * 4 + k] * y1[k];
            y2[i] = sigmoidf_(s);
        }
        out[0] = sigmoidf_(P3[0] * y2[0] + P3[1] * y2[1]);
    }
}

extern "C" void kernel_launch(void* const* d_in, const int* in_sizes, int n_in,
                              void* d_out, int out_size, void* d_ws, size_t ws_size,
                              hipStream_t stream) {
    const float* x1 = (const float*)d_in[0];
    const float* x2 = (const float*)d_in[1];
    const float* W0 = (const float*)d_in[2];
    const float* V  = (const float*)d_in[3];
    const float* W  = (const float*)d_in[4];
    const float* b  = (const float*)d_in[5];
    const float* P0 = (const float*)d_in[6];
    const float* P1 = (const float*)d_in[7];
    const float* P2 = (const float*)d_in[8];
    const float* P3 = (const float*)d_in[9];
    float* ws  = (float*)d_ws;
    float* out = (float*)d_out;
    int N1 = in_sizes[0] / DD;   // 120000
    int N2 = in_sizes[1] / DD;   // 100000

    k_zero <<<55,   256, 0, stream>>>(ws);
    k_mean <<<1024, 256, 0, stream>>>(x1, x2, N1, N2, ws);
    k_h    <<<2,    256, 0, stream>>>(W0, ws, OFF_SUMREP, OFF_H1, N1, N2);
    k_att1 <<<1024, 256, 0, stream>>>(x1, x2, N1, N2, ws);
    k_h    <<<2,    256, 0, stream>>>(W0, ws, OFF_S1REP, OFF_H2, N1, N2);
    k_att2 <<<1024, 256, 0, stream>>>(x1, x2, N1, N2, ws);
    k_comb <<<1,    512, 0, stream>>>(ws);
    k_ntn  <<<512,  256, 0, stream>>>(W, ws);
    k_final<<<1,    256, 0, stream>>>(V, b, P0, P1, P2, P3, ws, out);
}

// Round 2
// 418.691 us; speedup vs baseline: 1.0205x; 1.0205x over previous
//
#include <hip/hip_runtime.h>
#include <math.h>

// Problem constants (from reference): D=256, DIN=512, F=16
#define DD 256
#define REPS 8   // replicated accumulators to reduce atomic same-address contention

// Workspace layout (float offsets)
#define OFF_SUMREP 0        // 2 inputs * REPS * 256 = 4096
#define OFF_H1P    4096     // 2 * 256 = 512   (pre-tanh partial sums, atomic target)
#define OFF_S1REP  4608     // 4096
#define OFF_H2P    8704     // 512
#define OFF_OREP   9216     // 4096
#define OFF_O      13312    // 512  (o1 then o2)
#define OFF_WTREP  13824    // REPS * 16 = 128
#define WS_FLOATS  13952

__device__ __forceinline__ float sigmoidf_(float x) { return 1.0f / (1.0f + __expf(-x)); }
__device__ __forceinline__ float dot4(float4 a, float4 b) {
    return a.x * b.x + a.y * b.y + a.z * b.z + a.w * b.w;
}
__device__ __forceinline__ void fma4(float4& acc, float s, float4 v) {
    acc.x += s * v.x; acc.y += s * v.y; acc.z += s * v.z; acc.w += s * v.w;
}
__device__ __forceinline__ float wave_sum(float v) {
#pragma unroll
    for (int off = 32; off; off >>= 1) v += __shfl_xor(v, off, 64);
    return v;
}

__global__ void k_zero(float* __restrict__ ws) {
    int i = blockIdx.x * 256 + threadIdx.x;
    if (i < WS_FLOATS) ws[i] = 0.0f;
}

// Block-level float4 reduce of 4 waves + replicated atomic finish.
__device__ __forceinline__ void block_reduce_atomic(float4 acc, int t, float* dst_base) {
    __shared__ float4 lds[256];
    lds[t] = acc;
    __syncthreads();
    if (t < 64) {
        float4 s = lds[t];
        float4 a = lds[t + 64], c = lds[t + 128], d = lds[t + 192];
        s.x += a.x + c.x + d.x; s.y += a.y + c.y + d.y;
        s.z += a.z + c.z + d.z; s.w += a.w + c.w + d.w;
        float* dst = dst_base + t * 4;
        atomicAdd(dst + 0, s.x); atomicAdd(dst + 1, s.y);
        atomicAdd(dst + 2, s.z); atomicAdd(dst + 3, s.w);
    }
}

// Pass A: column sums. Grid = 2048 blocks; [0,1024)->x1, [1024,2048)->x2.
// Contiguous row chunk per block; wave-per-row; 4 rows in flight per wave.
__global__ void __launch_bounds__(256, 8)
k_mean(const float* __restrict__ x1, const float* __restrict__ x2,
       int N1, int N2, float* __restrict__ ws) {
    int b = blockIdx.x, t = threadIdx.x;
    int inp = b >> 10;
    int bl = b & 1023;
    const float4* x = (const float4*)(inp ? x2 : x1);
    int N = inp ? N2 : N1;
    int chunk = (N + 1023) >> 10;
    int start = bl * chunk;
    int end = min(start + chunk, N);
    int lane = t & 63, w = t >> 6;
    float4 a0 = make_float4(0.f, 0.f, 0.f, 0.f), a1 = a0;
    int r = start + w;
    for (; r + 12 < end; r += 16) {
        const float4* p = x + (size_t)r * 64 + lane;
        float4 v0 = p[0], v1 = p[256], v2 = p[512], v3 = p[768];
        a0.x += v0.x + v1.x; a0.y += v0.y + v1.y; a0.z += v0.z + v1.z; a0.w += v0.w + v1.w;
        a1.x += v2.x + v3.x; a1.y += v2.y + v3.y; a1.z += v2.z + v3.z; a1.w += v2.w + v3.w;
    }
    for (; r < end; r += 4) {
        float4 v = x[(size_t)r * 64 + lane];
        a0.x += v.x; a0.y += v.y; a0.z += v.z; a0.w += v.w;
    }
    a0.x += a1.x; a0.y += a1.y; a0.z += a1.z; a0.w += a1.w;
    block_reduce_atomic(a0, t, ws + OFF_SUMREP + inp * (REPS * 256) + (bl & (REPS - 1)) * 256);
}

// hP[inp] += partial of (colsum/N) @ W0 over a 16-row slice of W0.
// Grid = 32 blocks: blockIdx = inp*16 + g. tanh applied by consumers.
__global__ void k_hpart(const float* __restrict__ W0, float* __restrict__ ws,
                        int srcOff, int dstOff, int N1, int N2) {
    int inp = blockIdx.x >> 4, g = blockIdx.x & 15;
    int t = threadIdx.x;
    __shared__ float temp[16];
    if (t < 16) {
        const float* src = ws + srcOff + inp * (REPS * 256) + g * 16 + t;
        float s = 0.f;
#pragma unroll
        for (int r = 0; r < REPS; r++) s += src[r * 256];
        temp[t] = s * (1.0f / (float)(inp ? N2 : N1));
    }
    __syncthreads();
    float p = 0.f;
#pragma unroll
    for (int j = 0; j < 16; j++) p += temp[j] * W0[(g * 16 + j) * 256 + t];
    atomicAdd(ws + dstOff + inp * 256 + t, p);
}

// Pass B: s1 = sum_i sigmoid(x_i . h1) * x_i.
__global__ void __launch_bounds__(256, 8)
k_att1(const float* __restrict__ x1, const float* __restrict__ x2,
       int N1, int N2, float* __restrict__ ws) {
    int b = blockIdx.x, t = threadIdx.x;
    int inp = b >> 10;
    int bl = b & 1023;
    const float4* x = (const float4*)(inp ? x2 : x1);
    int N = inp ? N2 : N1;
    int chunk = (N + 1023) >> 10;
    int start = bl * chunk;
    int end = min(start + chunk, N);
    int lane = t & 63, w = t >> 6;
    float4 hp = ((const float4*)(ws + OFF_H1P + inp * 256))[lane];
    float4 h1 = make_float4(tanhf(hp.x), tanhf(hp.y), tanhf(hp.z), tanhf(hp.w));
    float4 acc = make_float4(0.f, 0.f, 0.f, 0.f);
    int r = start + w;
    for (; r + 12 < end; r += 16) {
        const float4* p = x + (size_t)r * 64 + lane;
        float4 v0 = p[0], v1 = p[256], v2 = p[512], v3 = p[768];
        float d0 = dot4(v0, h1), d1 = dot4(v1, h1), d2 = dot4(v2, h1), d3 = dot4(v3, h1);
#pragma unroll
        for (int off = 32; off; off >>= 1) {
            d0 += __shfl_xor(d0, off, 64); d1 += __shfl_xor(d1, off, 64);
            d2 += __shfl_xor(d2, off, 64); d3 += __shfl_xor(d3, off, 64);
        }
        fma4(acc, sigmoidf_(d0), v0); fma4(acc, sigmoidf_(d1), v1);
        fma4(acc, sigmoidf_(d2), v2); fma4(acc, sigmoidf_(d3), v3);
    }
    for (; r < end; r += 4) {
        float4 v = x[(size_t)r * 64 + lane];
        float d = wave_sum(dot4(v, h1));
        fma4(acc, sigmoidf_(d), v);
    }
    block_reduce_atomic(acc, t, ws + OFF_S1REP + inp * (REPS * 256) + (bl & (REPS - 1)) * 256);
}

// Pass C: o = sum_i att1_i*att2_i*x_i, att2_i = sigmoid(att1_i * (x_i . h2)).
__global__ void __launch_bounds__(256, 8)
k_att2(const float* __restrict__ x1, const float* __restrict__ x2,
       int N1, int N2, float* __restrict__ ws) {
    int b = blockIdx.x, t = threadIdx.x;
    int inp = b >> 10;
    int bl = b & 1023;
    const float4* x = (const float4*)(inp ? x2 : x1);
    int N = inp ? N2 : N1;
    int chunk = (N + 1023) >> 10;
    int start = bl * chunk;
    int end = min(start + chunk, N);
    int lane = t & 63, w = t >> 6;
    float4 hp1 = ((const float4*)(ws + OFF_H1P + inp * 256))[lane];
    float4 hp2 = ((const float4*)(ws + OFF_H2P + inp * 256))[lane];
    float4 h1 = make_float4(tanhf(hp1.x), tanhf(hp1.y), tanhf(hp1.z), tanhf(hp1.w));
    float4 h2 = make_float4(tanhf(hp2.x), tanhf(hp2.y), tanhf(hp2.z), tanhf(hp2.w));
    float4 acc = make_float4(0.f, 0.f, 0.f, 0.f);
    int r = start + w;
    for (; r + 12 < end; r += 16) {
        const float4* p = x + (size_t)r * 64 + lane;
        float4 v0 = p[0], v1 = p[256], v2 = p[512], v3 = p[768];
        float d0 = dot4(v0, h1), d1 = dot4(v1, h1), d2 = dot4(v2, h1), d3 = dot4(v3, h1);
        float e0 = dot4(v0, h2), e1 = dot4(v1, h2), e2 = dot4(v2, h2), e3 = dot4(v3, h2);
#pragma unroll
        for (int off = 32; off; off >>= 1) {
            d0 += __shfl_xor(d0, off, 64); e0 += __shfl_xor(e0, off, 64);
            d1 += __shfl_xor(d1, off, 64); e1 += __shfl_xor(e1, off, 64);
            d2 += __shfl_xor(d2, off, 64); e2 += __shfl_xor(e2, off, 64);
            d3 += __shfl_xor(d3, off, 64); e3 += __shfl_xor(e3, off, 64);
        }
        float a1_0 = sigmoidf_(d0), a1_1 = sigmoidf_(d1), a1_2 = sigmoidf_(d2), a1_3 = sigmoidf_(d3);
        fma4(acc, a1_0 * sigmoidf_(a1_0 * e0), v0);
        fma4(acc, a1_1 * sigmoidf_(a1_1 * e1), v1);
        fma4(acc, a1_2 * sigmoidf_(a1_2 * e2), v2);
        fma4(acc, a1_3 * sigmoidf_(a1_3 * e3), v3);
    }
    for (; r < end; r += 4) {
        float4 v = x[(size_t)r * 64 + lane];
        float d = dot4(v, h1), e = dot4(v, h2);
#pragma unroll
        for (int off = 32; off; off >>= 1) {
            d += __shfl_xor(d, off, 64); e += __shfl_xor(e, off, 64);
        }
        float a1 = sigmoidf_(d);
        fma4(acc, a1 * sigmoidf_(a1 * e), v);
    }
    block_reduce_atomic(acc, t, ws + OFF_OREP + inp * (REPS * 256) + (bl & (REPS - 1)) * 256);
}

// Combine o replicas -> o1[256], o2[256]
__global__ void k_comb(float* __restrict__ ws) {
    int t = threadIdx.x;           // 512 threads
    int inp = t >> 8, c = t & 255;
    float s = 0.f;
#pragma unroll
    for (int r = 0; r < REPS; r++) s += ws[OFF_OREP + inp * (REPS * 256) + r * 256 + c];
    ws[OFF_O + t] = s;
}

// w_term[f] = sum_{d,e} g1[d] W[f,d,e] g2[e], g=[o,o] duplication folded.
// 8192 rows (f,d) of 512 floats. 512 blocks x 16 rows; wave-per-row, 4 rows/wave.
__global__ void __launch_bounds__(256, 8)
k_ntn(const float* __restrict__ W, float* __restrict__ ws) {
    int b = blockIdx.x, t = threadIdx.x;
    int lane = t & 63, w = t >> 6;
    const float* o1 = ws + OFF_O;
    float4 o2f = ((const float4*)(ws + OFF_O + 256))[lane];
    int f = b >> 5;                 // 32 blocks per feature map
    int r0 = b * 16 + w;            // rows r0, r0+4, r0+8, r0+12
    const float4* W4 = (const float4*)W;
    float p0, p1, p2, p3;
    {
        const float4* q0 = W4 + (size_t)r0 * 128 + lane;
        float4 a0 = q0[0],   c0 = q0[64];
        float4 a1 = q0[512], c1 = q0[576];
        float4 a2 = q0[1024], c2 = q0[1088];
        float4 a3 = q0[1536], c3 = q0[1600];
        p0 = (a0.x + c0.x) * o2f.x + (a0.y + c0.y) * o2f.y + (a0.z + c0.z) * o2f.z + (a0.w + c0.w) * o2f.w;
        p1 = (a1.x + c1.x) * o2f.x + (a1.y + c1.y) * o2f.y + (a1.z + c1.z) * o2f.z + (a1.w + c1.w) * o2f.w;
        p2 = (a2.x + c2.x) * o2f.x + (a2.y + c2.y) * o2f.y + (a2.z + c2.z) * o2f.z + (a2.w + c2.w) * o2f.w;
        p3 = (a3.x + c3.x) * o2f.x + (a3.y + c3.y) * o2f.y + (a3.z + c3.z) * o2f.z + (a3.w + c3.w) * o2f.w;
    }
#pragma unroll
    for (int off = 32; off; off >>= 1) {
        p0 += __shfl_xor(p0, off, 64); p1 += __shfl_xor(p1, off, 64);
        p2 += __shfl_xor(p2, off, 64); p3 += __shfl_xor(p3, off, 64);
    }
    if (lane == 0) {
        float* dst = ws + OFF_WTREP + (b & (REPS - 1)) * 16 + f;
        int d = r0 & 511;
        atomicAdd(dst, o1[d & 255] * p0
                     + o1[(d + 4) & 255] * p1
                     + o1[(d + 8) & 255] * p2
                     + o1[(d + 12) & 255] * p3);
    }
}

// v_term + w_term + b -> sigmoid -> 4-layer MLP -> out[0]
__global__ void k_final(const float* __restrict__ V, const float* __restrict__ bb,
                        const float* __restrict__ P0, const float* __restrict__ P1,
                        const float* __restrict__ P2, const float* __restrict__ P3,
                        float* __restrict__ ws, float* __restrict__ out) {
    int t = threadIdx.x;           // 256 threads
    const float* o = ws + OFF_O;
    int f = t >> 4, j = t & 15;
    float p = 0.f;
    for (int k = j; k < 1024; k += 16) {
        float cv = (k < 512) ? o[k & 255] : o[256 + (k & 255)];
        p += cv * V[f * 1024 + k];
    }
    __shared__ float red[256];
    __shared__ float sv[16];
    red[t] = p;
    __syncthreads();
    if (t < 16) {
        float v = 0.f;
#pragma unroll
        for (int q = 0; q < 16; q++) v += red[t * 16 + q];
        float wt = 0.f;
#pragma unroll
        for (int r = 0; r < REPS; r++) wt += ws[OFF_WTREP + r * 16 + t];
        sv[t] = sigmoidf_(v + wt + bb[t]);
    }
    __syncthreads();
    if (t == 0) {
        float y0[8], y1[4], y2[2];
#pragma unroll
        for (int i = 0; i < 8; i++) {
            float s = 0.f;
            for (int k = 0; k < 16; k++) s += P0[i * 16 + k] * sv[k];
            y0[i] = sigmoidf_(s);
        }
#pragma unroll
        for (int i = 0; i < 4; i++) {
            float s = 0.f;
            for (int k = 0; k < 8; k++) s += P1[i * 8 + k] * y0[k];
            y1[i] = sigmoidf_(s);
        }
#pragma unroll
        for (int i = 0; i < 2; i++) {
            float s = 0.f;
            for (int k = 0; k < 4; k++) s += P2[i * 4 + k] * y1[k];
            y2[i] = sigmoidf_(s);
        }
        out[0] = sigmoidf_(P3[0] * y2[0] + P3[1] * y2[1]);
    }
}

extern "C" void kernel_launch(void* const* d_in, const int* in_sizes, int n_in,
                              void* d_out, int out_size, void* d_ws, size_t ws_size,
                              hipStream_t stream) {
    const float* x1 = (const float*)d_in[0];
    const float* x2 = (const float*)d_in[1];
    const float* W0 = (const float*)d_in[2];
    const float* V  = (const float*)d_in[3];
    const float* W  = (const float*)d_in[4];
    const float* b  = (const float*)d_in[5];
    const float* P0 = (const float*)d_in[6];
    const float* P1 = (const float*)d_in[7];
    const float* P2 = (const float*)d_in[8];
    const float* P3 = (const float*)d_in[9];
    float* ws  = (float*)d_ws;
    float* out = (float*)d_out;
    int N1 = in_sizes[0] / DD;   // 120000
    int N2 = in_sizes[1] / DD;   // 100000

    k_zero  <<<55,   256, 0, stream>>>(ws);
    k_mean  <<<2048, 256, 0, stream>>>(x1, x2, N1, N2, ws);
    k_hpart <<<32,   256, 0, stream>>>(W0, ws, OFF_SUMREP, OFF_H1P, N1, N2);
    k_att1  <<<2048, 256, 0, stream>>>(x1, x2, N1, N2, ws);
    k_hpart <<<32,   256, 0, stream>>>(W0, ws, OFF_S1REP, OFF_H2P, N1, N2);
    k_att2  <<<2048, 256, 0, stream>>>(x1, x2, N1, N2, ws);
    k_comb  <<<1,    512, 0, stream>>>(ws);
    k_ntn   <<<512,  256, 0, stream>>>(W, ws);
    k_final <<<1,    256, 0, stream>>>(V, b, P0, P1, P2, P3, ws, out);
}

// Round 3
// 407.755 us; speedup vs baseline: 1.0478x; 1.0268x over previous
//
#include <hip/hip_runtime.h>
#include <math.h>

// Problem constants (from reference): D=256, DIN=512, F=16
#define DD 256
#define REPS 8   // replicated accumulators to reduce atomic same-address contention

// Workspace layout (float offsets)
#define OFF_SUMREP 0        // 2 inputs * REPS * 256 = 4096
#define OFF_H1P    4096     // 2 * 256 = 512   (pre-tanh partial sums, atomic target)
#define OFF_S1REP  4608     // 4096
#define OFF_H2P    8704     // 512
#define OFF_OREP   9216     // 4096
#define OFF_O      13312    // 512  (o1 then o2)
#define OFF_WTREP  13824    // REPS * 16 = 128
#define WS_FLOATS  13952

__device__ __forceinline__ float sigmoidf_(float x) { return 1.0f / (1.0f + __expf(-x)); }
__device__ __forceinline__ float dot4(float4 a, float4 b) {
    return a.x * b.x + a.y * b.y + a.z * b.z + a.w * b.w;
}
__device__ __forceinline__ void fma4(float4& acc, float s, float4 v) {
    acc.x += s * v.x; acc.y += s * v.y; acc.z += s * v.z; acc.w += s * v.w;
}
__device__ __forceinline__ void add4(float4& acc, float4 v) {
    acc.x += v.x; acc.y += v.y; acc.z += v.z; acc.w += v.w;
}
__device__ __forceinline__ float wave_sum(float v) {
#pragma unroll
    for (int off = 32; off; off >>= 1) v += __shfl_xor(v, off, 64);
    return v;
}

__global__ void k_zero(float* __restrict__ ws) {
    int i = blockIdx.x * 256 + threadIdx.x;
    if (i < WS_FLOATS) ws[i] = 0.0f;
}

// Block-level float4 reduce of 4 waves + replicated atomic finish.
__device__ __forceinline__ void block_reduce_atomic(float4 acc, int t, float* dst_base) {
    __shared__ float4 lds[256];
    lds[t] = acc;
    __syncthreads();
    if (t < 64) {
        float4 s = lds[t];
        add4(s, lds[t + 64]); add4(s, lds[t + 128]); add4(s, lds[t + 192]);
        float* dst = dst_base + t * 4;
        atomicAdd(dst + 0, s.x); atomicAdd(dst + 1, s.y);
        atomicAdd(dst + 2, s.z); atomicAdd(dst + 3, s.w);
    }
}

// Pass A: column sums. Grid = 2048 blocks; [0,1024)->x1, [1024,2048)->x2.
// Wave-per-row, 8 independent dwordx4 loads in flight per wave iteration.
__global__ void __launch_bounds__(256, 4)
k_mean(const float* __restrict__ x1, const float* __restrict__ x2,
       int N1, int N2, float* __restrict__ ws) {
    int b = blockIdx.x, t = threadIdx.x;
    int inp = b >> 10;
    int bl = b & 1023;
    const float4* x = (const float4*)(inp ? x2 : x1);
    int N = inp ? N2 : N1;
    int chunk = (N + 1023) >> 10;
    int start = bl * chunk;
    int end = min(start + chunk, N);
    int lane = t & 63, w = t >> 6;
    float4 a0 = make_float4(0.f, 0.f, 0.f, 0.f), a1 = a0;
    int r = start + w;
    for (; r + 28 < end; r += 32) {
        const float4* p = x + (size_t)r * 64 + lane;
        float4 v[8];
#pragma unroll
        for (int u = 0; u < 8; u++) v[u] = p[u * 256];   // rows r, r+4, ..., r+28
#pragma unroll
        for (int u = 0; u < 8; u += 2) { add4(a0, v[u]); add4(a1, v[u + 1]); }
    }
    for (; r < end; r += 4) add4(a0, x[(size_t)r * 64 + lane]);
    add4(a0, a1);
    block_reduce_atomic(a0, t, ws + OFF_SUMREP + inp * (REPS * 256) + (bl & (REPS - 1)) * 256);
}

// hP[inp] += partial of (colsum/N) @ W0 over a 16-row slice of W0.
// Grid = 32 blocks: blockIdx = inp*16 + g. tanh applied by consumers.
__global__ void k_hpart(const float* __restrict__ W0, float* __restrict__ ws,
                        int srcOff, int dstOff, int N1, int N2) {
    int inp = blockIdx.x >> 4, g = blockIdx.x & 15;
    int t = threadIdx.x;
    __shared__ float temp[16];
    if (t < 16) {
        const float* src = ws + srcOff + inp * (REPS * 256) + g * 16 + t;
        float s = 0.f;
#pragma unroll
        for (int r = 0; r < REPS; r++) s += src[r * 256];
        temp[t] = s * (1.0f / (float)(inp ? N2 : N1));
    }
    __syncthreads();
    float p = 0.f;
#pragma unroll
    for (int j = 0; j < 16; j++) p += temp[j] * W0[(g * 16 + j) * 256 + t];
    atomicAdd(ws + dstOff + inp * 256 + t, p);
}

// Pass B: s1 = sum_i sigmoid(x_i . h1) * x_i.  8 rows in flight per wave.
__global__ void __launch_bounds__(256, 4)
k_att1(const float* __restrict__ x1, const float* __restrict__ x2,
       int N1, int N2, float* __restrict__ ws) {
    int b = blockIdx.x, t = threadIdx.x;
    int inp = b >> 10;
    int bl = b & 1023;
    const float4* x = (const float4*)(inp ? x2 : x1);
    int N = inp ? N2 : N1;
    int chunk = (N + 1023) >> 10;
    int start = bl * chunk;
    int end = min(start + chunk, N);
    int lane = t & 63, w = t >> 6;
    float4 hp = ((const float4*)(ws + OFF_H1P + inp * 256))[lane];
    float4 h1 = make_float4(tanhf(hp.x), tanhf(hp.y), tanhf(hp.z), tanhf(hp.w));
    float4 acc = make_float4(0.f, 0.f, 0.f, 0.f);
    int r = start + w;
    for (; r + 28 < end; r += 32) {
        const float4* p = x + (size_t)r * 64 + lane;
        float4 v[8];
#pragma unroll
        for (int u = 0; u < 8; u++) v[u] = p[u * 256];
        float d[8];
#pragma unroll
        for (int u = 0; u < 8; u++) d[u] = dot4(v[u], h1);
#pragma unroll
        for (int off = 32; off; off >>= 1) {
#pragma unroll
            for (int u = 0; u < 8; u++) d[u] += __shfl_xor(d[u], off, 64);
        }
#pragma unroll
        for (int u = 0; u < 8; u++) fma4(acc, sigmoidf_(d[u]), v[u]);
    }
    for (; r < end; r += 4) {
        float4 v = x[(size_t)r * 64 + lane];
        float d = wave_sum(dot4(v, h1));
        fma4(acc, sigmoidf_(d), v);
    }
    block_reduce_atomic(acc, t, ws + OFF_S1REP + inp * (REPS * 256) + (bl & (REPS - 1)) * 256);
}

// Pass C: o = sum_i att1_i*att2_i*x_i, att2_i = sigmoid(att1_i * (x_i . h2)).
__global__ void __launch_bounds__(256, 4)
k_att2(const float* __restrict__ x1, const float* __restrict__ x2,
       int N1, int N2, float* __restrict__ ws) {
    int b = blockIdx.x, t = threadIdx.x;
    int inp = b >> 10;
    int bl = b & 1023;
    const float4* x = (const float4*)(inp ? x2 : x1);
    int N = inp ? N2 : N1;
    int chunk = (N + 1023) >> 10;
    int start = bl * chunk;
    int end = min(start + chunk, N);
    int lane = t & 63, w = t >> 6;
    float4 hp1 = ((const float4*)(ws + OFF_H1P + inp * 256))[lane];
    float4 hp2 = ((const float4*)(ws + OFF_H2P + inp * 256))[lane];
    float4 h1 = make_float4(tanhf(hp1.x), tanhf(hp1.y), tanhf(hp1.z), tanhf(hp1.w));
    float4 h2 = make_float4(tanhf(hp2.x), tanhf(hp2.y), tanhf(hp2.z), tanhf(hp2.w));
    float4 acc = make_float4(0.f, 0.f, 0.f, 0.f);
    int r = start + w;
    for (; r + 28 < end; r += 32) {
        const float4* p = x + (size_t)r * 64 + lane;
        float4 v[8];
#pragma unroll
        for (int u = 0; u < 8; u++) v[u] = p[u * 256];
        float d[8], e[8];
#pragma unroll
        for (int u = 0; u < 8; u++) { d[u] = dot4(v[u], h1); e[u] = dot4(v[u], h2); }
#pragma unroll
        for (int off = 32; off; off >>= 1) {
#pragma unroll
            for (int u = 0; u < 8; u++) {
                d[u] += __shfl_xor(d[u], off, 64);
                e[u] += __shfl_xor(e[u], off, 64);
            }
        }
#pragma unroll
        for (int u = 0; u < 8; u++) {
            float a1 = sigmoidf_(d[u]);
            fma4(acc, a1 * sigmoidf_(a1 * e[u]), v[u]);
        }
    }
    for (; r < end; r += 4) {
        float4 v = x[(size_t)r * 64 + lane];
        float d = dot4(v, h1), e = dot4(v, h2);
#pragma unroll
        for (int off = 32; off; off >>= 1) {
            d += __shfl_xor(d, off, 64); e += __shfl_xor(e, off, 64);
        }
        float a1 = sigmoidf_(d);
        fma4(acc, a1 * sigmoidf_(a1 * e), v);
    }
    block_reduce_atomic(acc, t, ws + OFF_OREP + inp * (REPS * 256) + (bl & (REPS - 1)) * 256);
}

// Combine o replicas -> o1[256], o2[256]
__global__ void k_comb(float* __restrict__ ws) {
    int t = threadIdx.x;           // 512 threads
    int inp = t >> 8, c = t & 255;
    float s = 0.f;
#pragma unroll
    for (int r = 0; r < REPS; r++) s += ws[OFF_OREP + inp * (REPS * 256) + r * 256 + c];
    ws[OFF_O + t] = s;
}

// w_term[f] = sum_{d,e} g1[d] W[f,d,e] g2[e], g=[o,o] duplication folded.
// 8192 rows (f,d) of 512 floats. 512 blocks x 16 rows; wave-per-row, 4 rows/wave
// (8 dwordx4 loads in flight).
__global__ void __launch_bounds__(256, 4)
k_ntn(const float* __restrict__ W, float* __restrict__ ws) {
    int b = blockIdx.x, t = threadIdx.x;
    int lane = t & 63, w = t >> 6;
    const float* o1 = ws + OFF_O;
    float4 o2f = ((const float4*)(ws + OFF_O + 256))[lane];
    int f = b >> 5;                 // 32 blocks per feature map
    int r0 = b * 16 + w;            // rows r0, r0+4, r0+8, r0+12
    const float4* W4 = (const float4*)W;
    const float4* q0 = W4 + (size_t)r0 * 128 + lane;
    float4 va[8];
#pragma unroll
    for (int u = 0; u < 4; u++) { va[2 * u] = q0[u * 512]; va[2 * u + 1] = q0[u * 512 + 64]; }
    float p0 = (va[0].x + va[1].x) * o2f.x + (va[0].y + va[1].y) * o2f.y
             + (va[0].z + va[1].z) * o2f.z + (va[0].w + va[1].w) * o2f.w;
    float p1 = (va[2].x + va[3].x) * o2f.x + (va[2].y + va[3].y) * o2f.y
             + (va[2].z + va[3].z) * o2f.z + (va[2].w + va[3].w) * o2f.w;
    float p2 = (va[4].x + va[5].x) * o2f.x + (va[4].y + va[5].y) * o2f.y
             + (va[4].z + va[5].z) * o2f.z + (va[4].w + va[5].w) * o2f.w;
    float p3 = (va[6].x + va[7].x) * o2f.x + (va[6].y + va[7].y) * o2f.y
             + (va[6].z + va[7].z) * o2f.z + (va[6].w + va[7].w) * o2f.w;
#pragma unroll
    for (int off = 32; off; off >>= 1) {
        p0 += __shfl_xor(p0, off, 64); p1 += __shfl_xor(p1, off, 64);
        p2 += __shfl_xor(p2, off, 64); p3 += __shfl_xor(p3, off, 64);
    }
    if (lane == 0) {
        float* dst = ws + OFF_WTREP + (b & (REPS - 1)) * 16 + f;
        int d = r0 & 511;
        atomicAdd(dst, o1[d & 255] * p0
                     + o1[(d + 4) & 255] * p1
                     + o1[(d + 8) & 255] * p2
                     + o1[(d + 12) & 255] * p3);
    }
}

// v_term + w_term + b -> sigmoid -> 4-layer MLP -> out[0]
__global__ void k_final(const float* __restrict__ V, const float* __restrict__ bb,
                        const float* __restrict__ P0, const float* __restrict__ P1,
                        const float* __restrict__ P2, const float* __restrict__ P3,
                        float* __restrict__ ws, float* __restrict__ out) {
    int t = threadIdx.x;           // 256 threads
    const float* o = ws + OFF_O;
    int f = t >> 4, j = t & 15;
    float p = 0.f;
    for (int k = j; k < 1024; k += 16) {
        float cv = (k < 512) ? o[k & 255] : o[256 + (k & 255)];
        p += cv * V[f * 1024 + k];
    }
    __shared__ float red[256];
    __shared__ float sv[16];
    red[t] = p;
    __syncthreads();
    if (t < 16) {
        float v = 0.f;
#pragma unroll
        for (int q = 0; q < 16; q++) v += red[t * 16 + q];
        float wt = 0.f;
#pragma unroll
        for (int r = 0; r < REPS; r++) wt += ws[OFF_WTREP + r * 16 + t];
        sv[t] = sigmoidf_(v + wt + bb[t]);
    }
    __syncthreads();
    if (t == 0) {
        float y0[8], y1[4], y2[2];
#pragma unroll
        for (int i = 0; i < 8; i++) {
            float s = 0.f;
            for (int k = 0; k < 16; k++) s += P0[i * 16 + k] * sv[k];
            y0[i] = sigmoidf_(s);
        }
#pragma unroll
        for (int i = 0; i < 4; i++) {
            float s = 0.f;
            for (int k = 0; k < 8; k++) s += P1[i * 8 + k] * y0[k];
            y1[i] = sigmoidf_(s);
        }
#pragma unroll
        for (int i = 0; i < 2; i++) {
            float s = 0.f;
            for (int k = 0; k < 4; k++) s += P2[i * 4 + k] * y1[k];
            y2[i] = sigmoidf_(s);
        }
        out[0] = sigmoidf_(P3[0] * y2[0] + P3[1] * y2[1]);
    }
}

extern "C" void kernel_launch(void* const* d_in, const int* in_sizes, int n_in,
                              void* d_out, int out_size, void* d_ws, size_t ws_size,
                              hipStream_t stream) {
    const float* x1 = (const float*)d_in[0];
    const float* x2 = (const float*)d_in[1];
    const float* W0 = (const float*)d_in[2];
    const float* V  = (const float*)d_in[3];
    const float* W  = (const float*)d_in[4];
    const float* b  = (const float*)d_in[5];
    const float* P0 = (const float*)d_in[6];
    const float* P1 = (const float*)d_in[7];
    const float* P2 = (const float*)d_in[8];
    const float* P3 = (const float*)d_in[9];
    float* ws  = (float*)d_ws;
    float* out = (float*)d_out;
    int N1 = in_sizes[0] / DD;   // 120000
    int N2 = in_sizes[1] / DD;   // 100000

    k_zero  <<<55,   256, 0, stream>>>(ws);
    k_mean  <<<2048, 256, 0, stream>>>(x1, x2, N1, N2, ws);
    k_hpart <<<32,   256, 0, stream>>>(W0, ws, OFF_SUMREP, OFF_H1P, N1, N2);
    k_att1  <<<2048, 256, 0, stream>>>(x1, x2, N1, N2, ws);
    k_hpart <<<32,   256, 0, stream>>>(W0, ws, OFF_S1REP, OFF_H2P, N1, N2);
    k_att2  <<<2048, 256, 0, stream>>>(x1, x2, N1, N2, ws);
    k_comb  <<<1,    512, 0, stream>>>(ws);
    k_ntn   <<<512,  256, 0, stream>>>(W, ws);
    k_final <<<1,    256, 0, stream>>>(V, b, P0, P1, P2, P3, ws, out);
}